// Round 3
// baseline (164.496 us; speedup 1.0000x reference)
//
#include <hip/hip_runtime.h>
#include <cstdint>
#include <cstddef>

// Problem constants: B=64, R=36, W=32, D=1024
// A = [s;x] : 4096 x 1024 (rows 0..2047 = s words, 2048..4095 = x words)
// B = im    : 2304 x 1024
// dot       : 4096 x 2304 (bf16)

typedef __attribute__((ext_vector_type(8))) short short8;
typedef __attribute__((ext_vector_type(4))) float f32x4;

__device__ __forceinline__ unsigned short f2bf(float f) {
  unsigned u = __float_as_uint(f);
  u += 0x7FFFu + ((u >> 16) & 1u);
  return (unsigned short)(u >> 16);
}
__device__ __forceinline__ float bf2f(unsigned short h) {
  return __uint_as_float(((unsigned)h) << 16);
}
__device__ __forceinline__ float rcpf(float x) { return __builtin_amdgcn_rcpf(x); }

// ---------------- K1: convert fp32 -> bf16 rows + row L2 norms ----------------
__global__ __launch_bounds__(256) void k_prep(const float* __restrict__ s,
                                              const float* __restrict__ x,
                                              const float* __restrict__ im,
                                              unsigned short* __restrict__ Ab,
                                              unsigned short* __restrict__ Bb,
                                              float* __restrict__ w1,
                                              float* __restrict__ xn,
                                              float* __restrict__ imn) {
  int row = blockIdx.x, tid = threadIdx.x;
  const float* src; unsigned short* dst; float* np;
  if (row < 2048)      { src = s  + (size_t)row * 1024;          dst = Ab + (size_t)row * 1024;          np = w1  + row; }
  else if (row < 4096) { src = x  + (size_t)(row - 2048) * 1024; dst = Ab + (size_t)row * 1024;          np = xn  + (row - 2048); }
  else                 { src = im + (size_t)(row - 4096) * 1024; dst = Bb + (size_t)(row - 4096) * 1024; np = imn + (row - 4096); }
  float4 f = ((const float4*)src)[tid];
  ushort4 h;
  h.x = f2bf(f.x); h.y = f2bf(f.y); h.z = f2bf(f.z); h.w = f2bf(f.w);
  ((ushort4*)dst)[tid] = h;
  float p = f.x*f.x + f.y*f.y + f.z*f.z + f.w*f.w;
  #pragma unroll
  for (int o = 32; o > 0; o >>= 1) p += __shfl_down(p, o, 64);
  __shared__ float red[4];
  if ((tid & 63) == 0) red[tid >> 6] = p;
  __syncthreads();
  if (tid == 0) *np = sqrtf(red[0] + red[1] + red[2] + red[3]);
}

// ---------------- K2: per-image Gram G[i] = im_i @ im_i^T ----------------
__global__ __launch_bounds__(256) void k_gram(const float* __restrict__ im,
                                              float* __restrict__ G) {
  int b = blockIdx.x, r = blockIdx.y;
  int wid = threadIdx.x >> 6, l = threadIdx.x & 63;
  const float* rowr = im + ((size_t)b*36 + r) * 1024;
  float4 my[4];
  #pragma unroll
  for (int j = 0; j < 4; ++j) my[j] = ((const float4*)rowr)[j*64 + l];
  float* Gr = G + ((size_t)b*36 + r) * 36;
  for (int rp = wid; rp < 36; rp += 4) {
    const float* rowp = im + ((size_t)b*36 + rp) * 1024;
    float p = 0.f;
    #pragma unroll
    for (int j = 0; j < 4; ++j) {
      float4 u = ((const float4*)rowp)[j*64 + l];
      p += my[j].x*u.x + my[j].y*u.y + my[j].z*u.z + my[j].w*u.w;
    }
    #pragma unroll
    for (int o = 32; o > 0; o >>= 1) p += __shfl_down(p, o, 64);
    if (l == 0) Gr[rp] = p;
  }
}

// ---------------- K3: bf16 MFMA GEMM (m97 structure): dot = A @ B^T ----------------
__global__ __launch_bounds__(256) void k_gemm_mfma(const unsigned short* __restrict__ A,
                                                   const unsigned short* __restrict__ B,
                                                   unsigned short* __restrict__ dot) {
  __shared__ unsigned short lA[128 * 32];
  __shared__ unsigned short lB[128 * 32];
  int tid = threadIdx.x;
  int bn = blockIdx.x * 128, bm = blockIdx.y * 128;
  int wid = tid >> 6, l = tid & 63;
  int wr = (wid >> 1) * 64, wc = (wid & 1) * 64;
  int lr = l & 15, lq = l >> 4;

  f32x4 acc[4][4] = {};

  int row_a = tid >> 2;
  int kq = (tid & 3) * 8;
  const unsigned short* gA = A + (size_t)(bm + row_a) * 1024 + kq;
  const unsigned short* gB = B + (size_t)(bn + row_a) * 1024 + kq;
  unsigned loff = (unsigned)tid * 16u;

  for (int kt = 0; kt < 1024; kt += 32) {
    __builtin_amdgcn_global_load_lds(
        (const __attribute__((address_space(1))) void*)(gA + kt),
        (__attribute__((address_space(3))) void*)((char*)lA + loff), 16, 0, 0);
    __builtin_amdgcn_global_load_lds(
        (const __attribute__((address_space(1))) void*)(gA + 64*1024 + kt),
        (__attribute__((address_space(3))) void*)((char*)lA + 4096 + loff), 16, 0, 0);
    __builtin_amdgcn_global_load_lds(
        (const __attribute__((address_space(1))) void*)(gB + kt),
        (__attribute__((address_space(3))) void*)((char*)lB + loff), 16, 0, 0);
    __builtin_amdgcn_global_load_lds(
        (const __attribute__((address_space(1))) void*)(gB + 64*1024 + kt),
        (__attribute__((address_space(3))) void*)((char*)lB + 4096 + loff), 16, 0, 0);
    __syncthreads();

    short8 af[4], bfr[4];
    #pragma unroll
    for (int mi = 0; mi < 4; ++mi)
      af[mi] = *(const short8*)&lA[(wr + mi*16 + lr) * 32 + lq * 8];
    #pragma unroll
    for (int ni = 0; ni < 4; ++ni)
      bfr[ni] = *(const short8*)&lB[(wc + ni*16 + lr) * 32 + lq * 8];
    #pragma unroll
    for (int mi = 0; mi < 4; ++mi)
      #pragma unroll
      for (int ni = 0; ni < 4; ++ni)
        acc[mi][ni] = __builtin_amdgcn_mfma_f32_16x16x32_bf16(af[mi], bfr[ni], acc[mi][ni], 0, 0, 0);
    __syncthreads();
  }

  #pragma unroll
  for (int mi = 0; mi < 4; ++mi)
    #pragma unroll
    for (int ni = 0; ni < 4; ++ni) {
      int gcol = bn + wc + ni*16 + lr;
      #pragma unroll
      for (int q = 0; q < 4; ++q) {
        int grow = bm + wr + mi*16 + lq*4 + q;
        dot[(size_t)grow * 2304 + gcol] = f2bf(acc[mi][ni][q]);
      }
    }
}

// ---------------- K4: per-pair scores + IPOT, TWO waves per pair ----------------
// block = 256 thr = 4 waves = 2 pairs. wave j in {0,1} owns r in [18j, 18j+18).
// lane l: h = l>>5, w = l&31; lane owns r = 18j + 9h + m, m in [0,9).
template<int C>
__device__ __forceinline__ float dpp_add(float v) {
  return v + __int_as_float(__builtin_amdgcn_mov_dpp(__float_as_int(v), C, 0xF, 0xF, true));
}
template<int C>
__device__ __forceinline__ float dpp_max(float v) {
  return fmaxf(v, __int_as_float(__builtin_amdgcn_mov_dpp(__float_as_int(v), C, 0xF, 0xF, true)));
}
__device__ __forceinline__ float bsum32(float v) {   // sum over lane bits 0..4
  v = dpp_add<0xB1>(v);
  v = dpp_add<0x4E>(v);
  v = dpp_add<0x141>(v);
  v = dpp_add<0x128>(v);
  v += __shfl_xor(v, 16, 64);
  return v;
}
__device__ __forceinline__ float bmax32(float v) {
  v = dpp_max<0xB1>(v);
  v = dpp_max<0x4E>(v);
  v = dpp_max<0x141>(v);
  v = dpp_max<0x128>(v);
  v = fmaxf(v, __shfl_xor(v, 16, 64));
  return v;
}

__global__ __launch_bounds__(256) void k_pair2(const unsigned short* __restrict__ dotb,
                                               const float* __restrict__ Gm,
                                               const float* __restrict__ w1m,
                                               const float* __restrict__ xnm,
                                               const float* __restrict__ imnm,
                                               float* __restrict__ S,
                                               float* __restrict__ Sot) {
  __shared__ float  xA[2][2][32];       // scalar-per-w exchange (mx, w2sq, final ot)
  __shared__ float2 xB[2][2][32];       // (sum, num) exchange
  __shared__ float  xD[2][2][2][32];    // IPOT delta partial, [parity][pair][j][w]
  __shared__ float  aS[2][32][37];      // a-matrix stage, pad 37 -> conflict-free

  int wid = threadIdx.x >> 6;
  int p = wid >> 1, j = wid & 1;
  int pair = blockIdx.x * 2 + p;        // 0..4095
  int c = pair >> 6, i = pair & 63;
  int l = threadIdx.x & 63;
  int h = l >> 5, w = l & 31;
  int r0 = j*18 + h*9;

  const unsigned short* drow = dotb + (size_t)(c*32 + w) * 2304 + i*36 + r0;
  const unsigned short* xrow = drow + (size_t)2048 * 2304;
  float w1  = w1m[c*32 + w];
  float xnw = xnm[c*32 + w] + 1e-12f;

  float d0[9], Cm[9];
  #pragma unroll
  for (int m = 0; m < 9; ++m) d0[m] = bf2f(drow[m]);
  #pragma unroll
  for (int m = 0; m < 9; ++m) {
    float xv  = bf2f(xrow[m]);
    float inm = imnm[i*36 + r0 + m] + 1e-12f;
    Cm[m] = 1.f - xv * rcpf(xnw * inm);
  }

  // ---- attention: leaky -> l2norm over w -> softmax over r (cross-wave) ----
  float f[9];
  #pragma unroll
  for (int m = 0; m < 9; ++m) f[m] = d0[m] > 0.f ? d0[m] : 0.1f * d0[m];
  #pragma unroll
  for (int m = 0; m < 9; ++m) {
    float t = bsum32(f[m] * f[m]);
    f[m] = f[m] * rcpf(__builtin_amdgcn_sqrtf(t) + 1e-8f);
  }
  float p9[9];
  float mx = -1e30f;
  #pragma unroll
  for (int m = 0; m < 9; ++m) { p9[m] = 9.f * f[m]; mx = fmaxf(mx, p9[m]); }
  mx = fmaxf(mx, __shfl_xor(mx, 32, 64));          // max over this wave's 18 r
  if (h == 0) xA[p][j][w] = mx;
  __syncthreads();                                  // B1
  mx = fmaxf(mx, xA[p][j^1][w]);                    // max over all 36 r

  float e[9];
  float sum0 = 0.f, sum1 = 0.f, nu0 = 0.f, nu1 = 0.f;
  #pragma unroll
  for (int m = 0; m < 9; ++m) {
    e[m] = __expf(p9[m] - mx);
    if (m & 1) { sum1 += e[m]; nu1 = fmaf(e[m], d0[m], nu1); }
    else       { sum0 += e[m]; nu0 = fmaf(e[m], d0[m], nu0); }
  }
  float sum = sum0 + sum1, numu = nu0 + nu1;
  sum  += __shfl_xor(sum, 32, 64);
  numu += __shfl_xor(numu, 32, 64);
  if (h == 0) xB[p][j][w] = make_float2(sum, numu);
  __syncthreads();                                  // B2
  float2 o = xB[p][j^1][w];
  sum += o.x; numu += o.y;
  float inv = rcpf(sum);
  float num = numu * inv;

  float a9[9];
  #pragma unroll
  for (int m = 0; m < 9; ++m) {
    a9[m] = e[m] * inv;
    aS[p][w][r0 + m] = a9[m];
  }
  __syncthreads();                                  // B3

  float afull[36];
  #pragma unroll
  for (int rr = 0; rr < 36; ++rr) afull[rr] = aS[p][w][rr];

  // ---- w2^2 = a^T G a, rows split across the 2 waves ----
  int iu = __builtin_amdgcn_readfirstlane(i);
  const float* Gi = Gm + (size_t)iu * 1296 + (size_t)j * 18 * 36;
  float w2p = 0.f;
  #pragma unroll
  for (int rp = 0; rp < 18; ++rp) {
    float in0 = 0.f, in1 = 0.f;
    #pragma unroll
    for (int rr = 0; rr < 36; rr += 2) {
      in0 = fmaf(Gi[rp*36 + rr],     afull[rr],     in0);
      in1 = fmaf(Gi[rp*36 + rr + 1], afull[rr + 1], in1);
    }
    w2p = fmaf(afull[j*18 + rp], in0 + in1, w2p);
  }
  if (h == 0) xA[p][j][w] = w2p;
  __syncthreads();                                  // B4
  float w2 = __builtin_amdgcn_sqrtf(w2p + xA[p][j^1][w]);
  float rs6 = 6.f * num * rcpf(fmaxf(w1 * w2, 1e-8f));

  // ---- LSE over w (in-wave; both waves compute identical value) ----
  float mw = bmax32(rs6);
  float se = bsum32(__expf(rs6 - mw));
  float sim = (mw + __logf(se)) * (1.f / 6.f);
  if (j == 0 && l == 0) S[i*64 + c] = sim;

  // ---- IPOT: 20 iterations; sigma in-wave, delta via LDS exchange ----
  float Am[9], Qm[9], sg[9];
  #pragma unroll
  for (int m = 0; m < 9; ++m) {
    Am[m] = __expf(-2.f * Cm[m]);
    Qm[m] = Am[m];
    sg[m] = 1.f / 36.f;
  }
  float delta = 0.f;
  for (int it = 0; it < 20; ++it) {
    float t0 = 0.f, t1 = 0.f;
    #pragma unroll
    for (int m = 0; m < 9; ++m) {
      if (m & 1) t1 = fmaf(Qm[m], sg[m], t1);
      else       t0 = fmaf(Qm[m], sg[m], t0);
    }
    float tp = t0 + t1;
    tp += __shfl_xor(tp, 32, 64);                   // this wave's 18 r
    if (h == 0) xD[it & 1][p][j][w] = tp;
    __syncthreads();
    tp += xD[it & 1][p][j^1][w];                    // all 36 r
    delta = rcpf(32.f * tp);
    #pragma unroll
    for (int m = 0; m < 9; ++m) {
      float q = bsum32(Qm[m] * delta);              // sum over w
      sg[m] = rcpf(36.f * q);
    }
    if (it < 19) {
      #pragma unroll
      for (int m = 0; m < 9; ++m) Qm[m] = delta * Am[m] * Qm[m] * sg[m];
    }
  }
  float ot = 0.f;
  #pragma unroll
  for (int m = 0; m < 9; ++m) ot = fmaf(Cm[m], delta * Qm[m] * sg[m], ot);
  ot = bsum32(ot);                                  // over w
  ot += __shfl_xor(ot, 32, 64);                     // over h
  if (l == 0) xA[p][j][0] = ot;                     // wave total
  __syncthreads();
  if (j == 0 && l == 0) Sot[i*64 + c] = -(xA[p][0][0] + xA[p][1][0]);
}

// ---------------- K5: final contrastive reduction ----------------
__global__ __launch_bounds__(256) void k_reduce(const float* __restrict__ Sg,
                                                const float* __restrict__ Sotg,
                                                float* __restrict__ outp) {
  __shared__ float s[4096];
  __shared__ float so[4096];
  __shared__ float red0[256], red1[256];
  int tid = threadIdx.x;
  for (int e = tid; e < 4096; e += 256) { s[e] = Sg[e]; so[e] = Sotg[e]; }
  __syncthreads();
  float m0 = 0.f, m1 = 0.f;
  if (tid < 64) {
    int i = tid;
    float di = s[i*65], dio = so[i*65];
    for (int c2 = 0; c2 < 64; ++c2) {
      if (c2 == i) continue;
      float cs  = fmaxf(0.2f + s[i*64 + c2]  - di,  0.f);
      float cso = fmaxf(0.2f + so[i*64 + c2] - dio, 0.f);
      m0 = fmaxf(m0, cs + 0.1f * cso);
      m1 = fmaxf(m1, cso);
    }
  } else if (tid < 128) {
    int c2 = tid - 64;
    float dc = s[c2*65], dco = so[c2*65];
    for (int i = 0; i < 64; ++i) {
      if (i == c2) continue;
      float cim  = fmaxf(0.2f + s[i*64 + c2]  - dc,  0.f);
      float cimo = fmaxf(0.2f + so[i*64 + c2] - dco, 0.f);
      m0 = fmaxf(m0, cim + 0.1f * cimo);
      m1 = fmaxf(m1, cimo);
    }
  }
  red0[tid] = m0; red1[tid] = m1;
  __syncthreads();
  if (tid == 0) {
    float a0 = 0.f, a1 = 0.f;
    for (int t = 0; t < 128; ++t) { a0 += red0[t]; a1 += red1[t]; }
    outp[0] = a0;
    outp[1] = a1;
  }
}

extern "C" void kernel_launch(void* const* d_in, const int* in_sizes, int n_in,
                              void* d_out, int out_size, void* d_ws, size_t ws_size,
                              hipStream_t stream) {
  (void)in_sizes; (void)n_in; (void)out_size; (void)ws_size;
  const float* im = (const float*)d_in[0];
  const float* s  = (const float*)d_in[1];
  // d_in[2] = s_l (uniform == W, unused)
  const float* x  = (const float*)d_in[3];
  float* out = (float*)d_out;

  unsigned short* Ab   = (unsigned short*)d_ws;              // 4096*1024 bf16
  unsigned short* Bb   = Ab + (size_t)4096 * 1024;           // 2304*1024 bf16
  unsigned short* dotb = Bb + (size_t)2304 * 1024;           // 4096*2304 bf16
  float* G   = (float*)(dotb + (size_t)4096 * 2304);         // 64*36*36
  float* w1  = G + 64*36*36;
  float* xn  = w1 + 2048;
  float* imn = xn + 2048;
  float* S   = imn + 2304;
  float* Sot = S + 4096;

  k_prep<<<dim3(6400), 256, 0, stream>>>(s, x, im, Ab, Bb, w1, xn, imn);
  k_gram<<<dim3(64, 36), 256, 0, stream>>>(im, G);
  k_gemm_mfma<<<dim3(18, 32), 256, 0, stream>>>(Ab, Bb, dotb);
  k_pair2<<<dim3(2048), 256, 0, stream>>>(dotb, G, w1, xn, imn, S, Sot);
  k_reduce<<<dim3(1), 256, 0, stream>>>(S, Sot, out);
}